// Round 26
// baseline (3620.805 us; speedup 1.0000x reference)
//
#include <hip/hip_runtime.h>
#include <hip/hip_bf16.h>
#include <math.h>

#define HDIM 128
#define IN_DIM 256

// ---------------- init ----------------
__global__ void r26_zero_kernel(int* deg, int* cursor, int n) {
  int i = blockIdx.x * blockDim.x + threadIdx.x;
  if (i < n) { deg[i] = 0; cursor[i] = 0; }
}

// ---------------- CSR build (by dst; (2,E) int32 edges; self-loops appended) ----------------
__global__ void r26_deg_kernel(const int* ei, int E, int N, int* deg) {
  int e = blockIdx.x * blockDim.x + threadIdx.x;
  int Et = E + N;
  if (e >= Et) return;
  int d = (e < E) ? ei[E + e] : (e - E);
  atomicAdd(&deg[d], 1);
}

__global__ __launch_bounds__(1024) void r26_scan_kernel(const int* deg, int* rowptr, int n) {
  __shared__ int lds[1024];
  __shared__ int carry;
  int tid = threadIdx.x;
  if (tid == 0) carry = 0;
  __syncthreads();
  for (int base = 0; base < n; base += 1024) {
    int v = (base + tid < n) ? deg[base + tid] : 0;
    lds[tid] = v;
    __syncthreads();
    for (int off = 1; off < 1024; off <<= 1) {
      int t = (tid >= off) ? lds[tid - off] : 0;
      __syncthreads();
      lds[tid] += t;
      __syncthreads();
    }
    if (base + tid < n) rowptr[base + tid] = carry + lds[tid] - v;
    __syncthreads();
    if (tid == 0) carry += lds[1023];
    __syncthreads();
  }
  if (tid == 0) rowptr[n] = carry;
}

__global__ void r26_fill_kernel(const int* ei, int E, int N,
                                const int* rowptr, int* cursor, int* csr) {
  int e = blockIdx.x * blockDim.x + threadIdx.x;
  int Et = E + N;
  if (e >= Et) return;
  int s, d;
  if (e < E) { s = ei[e]; d = ei[E + e]; } else { s = d = e - E; }
  int pos = atomicAdd(&cursor[d], 1);
  csr[rowptr[d] + pos] = s;
}

// ---------------- h1 = x[N,256] @ W1[256,128] (fp32) ----------------
__global__ void r26_gemm_x_kernel(const float* A, const float* W, float* out, int n) {
  int gid = blockIdx.x * blockDim.x + threadIdx.x;
  if (gid >= n * HDIM) return;
  int i = gid >> 7, j = gid & 127;
  float acc = 0.f;
  const float* a = A + (size_t)i * IN_DIM;
  for (int k = 0; k < IN_DIM; ++k)
    acc += a[k] * W[k * HDIM + j];
  out[gid] = acc;
}

// ---------------- K=128 GEMM ----------------
__global__ void r26_gemm_f_kernel(const float* A, const float* W, float* out, int n) {
  int gid = blockIdx.x * blockDim.x + threadIdx.x;
  if (gid >= n * HDIM) return;
  int i = gid >> 7, j = gid & 127;
  float acc = 0.f;
  const float* a = A + (size_t)i * HDIM;
  for (int k = 0; k < HDIM; ++k)
    acc += a[k] * W[k * HDIM + j];
  out[gid] = acc;
}

// ---------------- K=128 GEMM + bias + BN + ReLU ----------------
__global__ void r26_gemm_epi_kernel(const float* A, const float* W, const float* bias,
                                    const float* g, const float* be,
                                    const float* mean, const float* var,
                                    float* out, int n) {
  int gid = blockIdx.x * blockDim.x + threadIdx.x;
  if (gid >= n * HDIM) return;
  int i = gid >> 7, j = gid & 127;
  float acc = 0.f;
  const float* a = A + (size_t)i * HDIM;
  for (int k = 0; k < HDIM; ++k)
    acc += a[k] * W[k * HDIM + j];
  float o = acc + bias[j];
  float sc = rsqrtf(var[j] + 1e-5f) * g[j];
  o = (o - mean[j]) * sc + be[j];
  out[gid] = fmaxf(o, 0.f);
}

// ---------------- per-node attention scalars ----------------
__global__ void r26_alar_kernel(const float* h, const float* attl, const float* attr,
                                float* al, float* ar, int n) {
  int i = blockIdx.x * blockDim.x + threadIdx.x;
  if (i >= n) return;
  float l = 0.f, r = 0.f;
  const float* hv = h + (size_t)i * HDIM;
  for (int k = 0; k < HDIM; ++k) {
    l += hv[k] * attl[k];
    r += hv[k] * attr[k];
  }
  al[i] = l;
  ar[i] = r;
}

// ---------------- per-edge attention score (thread per dst node) ----------------
__global__ void r26_alpha_kernel(const float* h, const float* al, const float* ar,
                                 const int* rowptr, const int* csr, float* alp, int n) {
  int i = blockIdx.x * blockDim.x + threadIdx.x;
  if (i >= n) return;
  float ari = ar[i];
  const float* hi = h + (size_t)i * HDIM;
  int beg = rowptr[i], end = rowptr[i + 1];
  for (int e = beg; e < end; ++e) {
    int s = csr[e];
    const float* hs = h + (size_t)s * HDIM;
    float p = 0.f;
    for (int k = 0; k < HDIM; ++k) p += hi[k] * hs[k];
    float a = (al[s] + ari) * (1.f / (1.f + expf(-p)));
    alp[e] = (a > 0.f) ? a : 0.2f * a;   // leaky relu 0.2
  }
}

// ---------------- segment softmax normalize ----------------
__global__ void r26_norm_kernel(const int* rowptr, float* alp, int n) {
  int i = blockIdx.x * blockDim.x + threadIdx.x;
  if (i >= n) return;
  int beg = rowptr[i], end = rowptr[i + 1];
  float m = -INFINITY;
  for (int e = beg; e < end; ++e) m = fmaxf(m, alp[e]);
  float den = 0.f;
  for (int e = beg; e < end; ++e) den += expf(alp[e] - m);
  float inv = 1.f / den;
  for (int e = beg; e < end; ++e) alp[e] = expf(alp[e] - m) * inv;
}

// ---------------- PV + bias + BN + ReLU ----------------
__global__ void r26_pv_kernel(const float* h, const float* aw, const int* rowptr, const int* csr,
                              const float* bias, const float* g, const float* be,
                              const float* mean, const float* var,
                              float* out, int n) {
  int gid = blockIdx.x * blockDim.x + threadIdx.x;
  if (gid >= n * HDIM) return;
  int i = gid >> 7, ch = gid & 127;
  int beg = rowptr[i], end = rowptr[i + 1];
  float acc = 0.f;
  for (int e = beg; e < end; ++e)
    acc += aw[e] * h[(size_t)csr[e] * HDIM + ch];
  float o = acc + bias[ch];
  float sc = rsqrtf(var[ch] + 1e-5f) * g[ch];
  o = (o - mean[ch]) * sc + be[ch];
  out[gid] = fmaxf(o, 0.f);
}

// ---------------- fc3: out[N,2] = h @ fcw3[128,2] + fcb3  (FP32 output!) ----------------
__global__ void r26_fc3_kernel(const float* h, const float* w, const float* b,
                               float* out, int n) {
  int i = blockIdx.x * blockDim.x + threadIdx.x;
  if (i >= n) return;
  const float* hv = h + (size_t)i * HDIM;
  float p0 = 0.f, p1 = 0.f;
  for (int k = 0; k < HDIM; ++k) {
    p0 += hv[k] * w[2 * k];
    p1 += hv[k] * w[2 * k + 1];
  }
  out[2 * i]     = p0 + b[0];
  out[2 * i + 1] = p1 + b[1];
}

extern "C" void kernel_launch(void* const* d_in, const int* in_sizes, int n_in,
                              void* d_out, int out_size, void* d_ws, size_t ws_size,
                              hipStream_t stream) {
  const float* x     = (const float*)d_in[0];
  const int*   ei    = (const int*)d_in[1];
  const float* W1    = (const float*)d_in[2];
  const float* b1    = (const float*)d_in[3];
  const float* attl1 = (const float*)d_in[4];
  const float* attr1 = (const float*)d_in[5];
  const float* g1    = (const float*)d_in[6];
  const float* be1   = (const float*)d_in[7];
  const float* m1    = (const float*)d_in[8];
  const float* v1    = (const float*)d_in[9];
  const float* W2    = (const float*)d_in[10];
  const float* b2    = (const float*)d_in[11];
  const float* attl2 = (const float*)d_in[12];
  const float* attr2 = (const float*)d_in[13];
  const float* g2    = (const float*)d_in[14];
  const float* be2   = (const float*)d_in[15];
  const float* m2    = (const float*)d_in[16];
  const float* v2    = (const float*)d_in[17];
  const float* fcw1  = (const float*)d_in[18];
  const float* fcb1  = (const float*)d_in[19];
  const float* g3    = (const float*)d_in[20];
  const float* be3   = (const float*)d_in[21];
  const float* m3    = (const float*)d_in[22];
  const float* v3    = (const float*)d_in[23];
  const float* fcw2  = (const float*)d_in[24];
  const float* fcb2  = (const float*)d_in[25];
  const float* g4    = (const float*)d_in[26];
  const float* be4   = (const float*)d_in[27];
  const float* m4    = (const float*)d_in[28];
  const float* v4    = (const float*)d_in[29];
  const float* fcw3  = (const float*)d_in[30];
  const float* fcb3  = (const float*)d_in[31];

  int N  = in_sizes[0] / IN_DIM;
  int E  = in_sizes[1] / 2;
  int Et = E + N;

  char* wsb = (char*)d_ws;
  size_t off = 0;
  auto carve = [&](size_t bytes) -> char* {
    char* p = wsb + off;
    off += (bytes + 255) & ~(size_t)255;
    return p;
  };
  float* buf0   = (float*)carve((size_t)N * HDIM * 4);
  float* buf1   = (float*)carve((size_t)N * HDIM * 4);
  float* al     = (float*)carve((size_t)N * 4);
  float* ar     = (float*)carve((size_t)N * 4);
  int*   rowptr = (int*)carve((size_t)(N + 1) * 4);
  int*   deg    = (int*)carve((size_t)N * 4);
  int*   cursor = (int*)carve((size_t)N * 4);
  int*   csr    = (int*)carve((size_t)Et * 4);
  float* alp    = (float*)carve((size_t)Et * 4);

  int eb = (Et + 255) / 256;
  int nb = (N + 255) / 256;
  int gb = (N * HDIM + 255) / 256;

  r26_zero_kernel<<<nb, 256, 0, stream>>>(deg, cursor, N);
  r26_deg_kernel<<<eb, 256, 0, stream>>>(ei, E, N, deg);
  r26_scan_kernel<<<1, 1024, 0, stream>>>(deg, rowptr, N);
  r26_fill_kernel<<<eb, 256, 0, stream>>>(ei, E, N, rowptr, cursor, csr);

  // conv1
  r26_gemm_x_kernel<<<gb, 256, 0, stream>>>(x, W1, buf0, N);
  r26_alar_kernel<<<nb, 256, 0, stream>>>(buf0, attl1, attr1, al, ar, N);
  r26_alpha_kernel<<<nb, 256, 0, stream>>>(buf0, al, ar, rowptr, csr, alp, N);
  r26_norm_kernel<<<nb, 256, 0, stream>>>(rowptr, alp, N);
  r26_pv_kernel<<<gb, 256, 0, stream>>>(buf0, alp, rowptr, csr, b1, g1, be1, m1, v1, buf1, N);

  // conv2
  r26_gemm_f_kernel<<<gb, 256, 0, stream>>>(buf1, W2, buf0, N);
  r26_alar_kernel<<<nb, 256, 0, stream>>>(buf0, attl2, attr2, al, ar, N);
  r26_alpha_kernel<<<nb, 256, 0, stream>>>(buf0, al, ar, rowptr, csr, alp, N);
  r26_norm_kernel<<<nb, 256, 0, stream>>>(rowptr, alp, N);
  r26_pv_kernel<<<gb, 256, 0, stream>>>(buf0, alp, rowptr, csr, b2, g2, be2, m2, v2, buf1, N);

  // fc1 + BN3 + ReLU ; fc2 + BN4 + ReLU ; fc3 (fp32 out)
  r26_gemm_epi_kernel<<<gb, 256, 0, stream>>>(buf1, fcw1, fcb1, g3, be3, m3, v3, buf0, N);
  r26_gemm_epi_kernel<<<gb, 256, 0, stream>>>(buf0, fcw2, fcb2, g4, be4, m4, v4, buf1, N);
  r26_fc3_kernel<<<nb, 256, 0, stream>>>(buf1, fcw3, fcb3, (float*)d_out, N);
}

// Round 27
// 1063.330 us; speedup vs baseline: 3.4052x; 3.4052x over previous
//
#include <hip/hip_runtime.h>
#include <hip/hip_bf16.h>
#include <math.h>

#define HDIM 128
#define IN_DIM 256

// ---------------- init ----------------
__global__ void r27_zero_kernel(int* deg, int* cursor, int n) {
  int i = blockIdx.x * blockDim.x + threadIdx.x;
  if (i < n) { deg[i] = 0; cursor[i] = 0; }
}

// ---------------- CSR build (by dst; (2,E) int32; self-loops appended) ----------------
__global__ void r27_deg_kernel(const int* ei, int E, int N, int* deg) {
  int e = blockIdx.x * blockDim.x + threadIdx.x;
  int Et = E + N;
  if (e >= Et) return;
  int d = (e < E) ? ei[E + e] : (e - E);
  atomicAdd(&deg[d], 1);
}

// hierarchical exclusive scan: chunk scan -> chunk-sum scan -> add offsets
__global__ __launch_bounds__(1024) void r27_scan1_kernel(const int* deg, int* rowptr,
                                                         int* bsum, int n) {
  __shared__ int lds[1024];
  int tid = threadIdx.x;
  int base = blockIdx.x * 1024;
  int v = (base + tid < n) ? deg[base + tid] : 0;
  lds[tid] = v;
  __syncthreads();
  for (int off = 1; off < 1024; off <<= 1) {
    int t = (tid >= off) ? lds[tid - off] : 0;
    __syncthreads();
    lds[tid] += t;
    __syncthreads();
  }
  if (base + tid < n) rowptr[base + tid] = lds[tid] - v;   // exclusive within chunk
  if (tid == 0) bsum[blockIdx.x] = lds[1023];
}
__global__ void r27_scan2_kernel(int* bsum, int* boff, int nb, int* rowptr, int n) {
  if (blockIdx.x != 0 || threadIdx.x != 0) return;
  int acc = 0;
  for (int b = 0; b < nb; ++b) { boff[b] = acc; acc += bsum[b]; }
  rowptr[n] = acc;
}
__global__ void r27_scan3_kernel(int* rowptr, const int* boff, int n) {
  int i = blockIdx.x * blockDim.x + threadIdx.x;
  if (i < n) rowptr[i] += boff[i >> 10];
}

__global__ void r27_fill_kernel(const int* ei, int E, int N,
                                const int* rowptr, int* cursor, int* csr) {
  int e = blockIdx.x * blockDim.x + threadIdx.x;
  int Et = E + N;
  if (e >= Et) return;
  int s, d;
  if (e < E) { s = ei[e]; d = ei[E + e]; } else { s = d = e - E; }
  int pos = atomicAdd(&cursor[d], 1);
  csr[rowptr[d] + pos] = s;
}

// ---------------- tiled GEMM: out[N,128] = A[N,K] @ W[K,128] (+optional epi) ----------------
template<int K, bool EPI>
__global__ __launch_bounds__(128) void r27_gemm_kernel(const float* __restrict__ A,
                                                       const float* __restrict__ W,
                                                       const float* __restrict__ bias,
                                                       const float* __restrict__ g,
                                                       const float* __restrict__ be,
                                                       const float* __restrict__ mean,
                                                       const float* __restrict__ var,
                                                       float* __restrict__ out, int n) {
  __shared__ float a[8][K];
  int row0 = blockIdx.x * 8;
  int tid = threadIdx.x;
  // cooperative float4 stage of 8 A-rows
  for (int idx = tid; idx < 8 * K / 4; idx += 128) {
    int r = idx / (K / 4), c4 = idx - r * (K / 4);
    int row = row0 + r;
    float4 v = (row < n) ? *(const float4*)&A[(size_t)row * K + 4 * c4]
                         : make_float4(0.f, 0.f, 0.f, 0.f);
    *(float4*)&a[r][4 * c4] = v;
  }
  __syncthreads();
  float acc[8] = {0.f, 0.f, 0.f, 0.f, 0.f, 0.f, 0.f, 0.f};
  #pragma unroll 4
  for (int k = 0; k < K; ++k) {
    float w = W[(size_t)k * HDIM + tid];
    #pragma unroll
    for (int r = 0; r < 8; ++r) acc[r] += a[r][k] * w;
  }
  float bi = 0.f, sc = 1.f, sh = 0.f;
  if (EPI) {
    bi = bias[tid];
    sc = rsqrtf(var[tid] + 1e-5f) * g[tid];
    sh = be[tid] - mean[tid] * sc;
  }
  #pragma unroll
  for (int r = 0; r < 8; ++r) {
    int row = row0 + r;
    if (row >= n) break;
    float o = acc[r];
    if (EPI) { o = (o + bi) * sc + sh; o = fmaxf(o, 0.f); }
    out[(size_t)row * HDIM + tid] = o;
  }
}

// ---------------- wave-parallel per-node attention scalars ----------------
__global__ __launch_bounds__(256) void r27_alar_kernel(const float* __restrict__ h,
                                                       const float* __restrict__ attl,
                                                       const float* __restrict__ attr,
                                                       float* __restrict__ al,
                                                       float* __restrict__ ar, int n) {
  int wid = threadIdx.x >> 6, lane = threadIdx.x & 63;
  int i = blockIdx.x * 4 + wid;
  if (i >= n) return;
  float2 hv = *(const float2*)&h[(size_t)i * HDIM + 2 * lane];
  float l = hv.x * attl[2 * lane] + hv.y * attl[2 * lane + 1];
  float r = hv.x * attr[2 * lane] + hv.y * attr[2 * lane + 1];
  #pragma unroll
  for (int off = 32; off > 0; off >>= 1) {
    l += __shfl_xor(l, off, 64);
    r += __shfl_xor(r, off, 64);
  }
  if (lane == 0) { al[i] = l; ar[i] = r; }
}

// ---------------- fused edge aggregation: online segment-softmax + PV + bias/BN/ReLU ----------------
__global__ __launch_bounds__(256) void r27_agg_kernel(const float* __restrict__ h,
                                                      const float* __restrict__ al,
                                                      const float* __restrict__ ar,
                                                      const int* __restrict__ rowptr,
                                                      const int* __restrict__ csr,
                                                      const float* __restrict__ bias,
                                                      const float* __restrict__ g,
                                                      const float* __restrict__ be,
                                                      const float* __restrict__ mean,
                                                      const float* __restrict__ var,
                                                      float* __restrict__ out, int n) {
  int wid = threadIdx.x >> 6, lane = threadIdx.x & 63;
  int i = blockIdx.x * 4 + wid;
  if (i >= n) return;
  float2 hi = *(const float2*)&h[(size_t)i * HDIM + 2 * lane];
  float ari = ar[i];
  int beg = rowptr[i], end = rowptr[i + 1];
  float mrun = -INFINITY, den = 0.f, acc0 = 0.f, acc1 = 0.f;
  for (int e = beg; e < end; ++e) {
    int s = csr[e];
    float2 hs = *(const float2*)&h[(size_t)s * HDIM + 2 * lane];
    float p = hi.x * hs.x + hi.y * hs.y;
    #pragma unroll
    for (int off = 32; off > 0; off >>= 1) p += __shfl_xor(p, off, 64);
    float a = (al[s] + ari) * (1.f / (1.f + __expf(-p)));
    a = (a > 0.f) ? a : 0.2f * a;            // leaky relu 0.2
    if (a > mrun) {                           // wave-uniform (p reduced across wave)
      float c = __expf(mrun - a);             // exp(-inf)=0 on first edge
      den *= c; acc0 *= c; acc1 *= c;
      mrun = a;
    }
    float w = __expf(a - mrun);
    den += w;
    acc0 += w * hs.x;
    acc1 += w * hs.y;
  }
  float inv = 1.f / den;
  int d0 = 2 * lane, d1 = d0 + 1;
  float o0 = acc0 * inv + bias[d0];
  float o1 = acc1 * inv + bias[d1];
  float sc0 = rsqrtf(var[d0] + 1e-5f) * g[d0];
  float sc1 = rsqrtf(var[d1] + 1e-5f) * g[d1];
  o0 = (o0 - mean[d0]) * sc0 + be[d0];
  o1 = (o1 - mean[d1]) * sc1 + be[d1];
  o0 = fmaxf(o0, 0.f);
  o1 = fmaxf(o1, 0.f);
  *(float2*)&out[(size_t)i * HDIM + 2 * lane] = make_float2(o0, o1);
}

// ---------------- wave-parallel fc3 (fp32 out) ----------------
__global__ __launch_bounds__(256) void r27_fc3_kernel(const float* __restrict__ h,
                                                      const float* __restrict__ w,
                                                      const float* __restrict__ b,
                                                      float* __restrict__ out, int n) {
  int wid = threadIdx.x >> 6, lane = threadIdx.x & 63;
  int i = blockIdx.x * 4 + wid;
  if (i >= n) return;
  float2 hv = *(const float2*)&h[(size_t)i * HDIM + 2 * lane];
  int k0 = 2 * lane, k1 = k0 + 1;
  float p0 = hv.x * w[2 * k0] + hv.y * w[2 * k1];
  float p1 = hv.x * w[2 * k0 + 1] + hv.y * w[2 * k1 + 1];
  #pragma unroll
  for (int off = 32; off > 0; off >>= 1) {
    p0 += __shfl_xor(p0, off, 64);
    p1 += __shfl_xor(p1, off, 64);
  }
  if (lane == 0) {
    out[2 * i]     = p0 + b[0];
    out[2 * i + 1] = p1 + b[1];
  }
}

extern "C" void kernel_launch(void* const* d_in, const int* in_sizes, int n_in,
                              void* d_out, int out_size, void* d_ws, size_t ws_size,
                              hipStream_t stream) {
  const float* x     = (const float*)d_in[0];
  const int*   ei    = (const int*)d_in[1];
  const float* W1    = (const float*)d_in[2];
  const float* b1    = (const float*)d_in[3];
  const float* attl1 = (const float*)d_in[4];
  const float* attr1 = (const float*)d_in[5];
  const float* g1    = (const float*)d_in[6];
  const float* be1   = (const float*)d_in[7];
  const float* m1    = (const float*)d_in[8];
  const float* v1    = (const float*)d_in[9];
  const float* W2    = (const float*)d_in[10];
  const float* b2    = (const float*)d_in[11];
  const float* attl2 = (const float*)d_in[12];
  const float* attr2 = (const float*)d_in[13];
  const float* g2    = (const float*)d_in[14];
  const float* be2   = (const float*)d_in[15];
  const float* m2    = (const float*)d_in[16];
  const float* v2    = (const float*)d_in[17];
  const float* fcw1  = (const float*)d_in[18];
  const float* fcb1  = (const float*)d_in[19];
  const float* g3    = (const float*)d_in[20];
  const float* be3   = (const float*)d_in[21];
  const float* m3    = (const float*)d_in[22];
  const float* v3    = (const float*)d_in[23];
  const float* fcw2  = (const float*)d_in[24];
  const float* fcb2  = (const float*)d_in[25];
  const float* g4    = (const float*)d_in[26];
  const float* be4   = (const float*)d_in[27];
  const float* m4    = (const float*)d_in[28];
  const float* v4    = (const float*)d_in[29];
  const float* fcw3  = (const float*)d_in[30];
  const float* fcb3  = (const float*)d_in[31];

  int N  = in_sizes[0] / IN_DIM;
  int E  = in_sizes[1] / 2;
  int Et = E + N;

  char* wsb = (char*)d_ws;
  size_t off = 0;
  auto carve = [&](size_t bytes) -> char* {
    char* p = wsb + off;
    off += (bytes + 255) & ~(size_t)255;
    return p;
  };
  float* buf0   = (float*)carve((size_t)N * HDIM * 4);
  float* buf1   = (float*)carve((size_t)N * HDIM * 4);
  float* al     = (float*)carve((size_t)N * 4);
  float* ar     = (float*)carve((size_t)N * 4);
  int*   rowptr = (int*)carve((size_t)(N + 1) * 4);
  int*   deg    = (int*)carve((size_t)N * 4);
  int*   cursor = (int*)carve((size_t)N * 4);
  int*   csr    = (int*)carve((size_t)Et * 4);
  int*   bsum   = (int*)carve(4096);
  int*   boff   = (int*)carve(4096);

  int eb  = (Et + 255) / 256;
  int nb  = (N + 255) / 256;
  int gb  = (N + 7) / 8;
  int nb4 = (N + 3) / 4;
  int sb  = (N + 1023) / 1024;

  // CSR build
  r27_zero_kernel<<<nb, 256, 0, stream>>>(deg, cursor, N);
  r27_deg_kernel<<<eb, 256, 0, stream>>>(ei, E, N, deg);
  r27_scan1_kernel<<<sb, 1024, 0, stream>>>(deg, rowptr, bsum, N);
  r27_scan2_kernel<<<1, 64, 0, stream>>>(bsum, boff, sb, rowptr, N);
  r27_scan3_kernel<<<nb, 256, 0, stream>>>(rowptr, boff, N);
  r27_fill_kernel<<<eb, 256, 0, stream>>>(ei, E, N, rowptr, cursor, csr);

  // conv1
  r27_gemm_kernel<IN_DIM, false><<<gb, 128, 0, stream>>>(x, W1, nullptr, nullptr, nullptr, nullptr, nullptr, buf0, N);
  r27_alar_kernel<<<nb4, 256, 0, stream>>>(buf0, attl1, attr1, al, ar, N);
  r27_agg_kernel<<<nb4, 256, 0, stream>>>(buf0, al, ar, rowptr, csr, b1, g1, be1, m1, v1, buf1, N);

  // conv2
  r27_gemm_kernel<HDIM, false><<<gb, 128, 0, stream>>>(buf1, W2, nullptr, nullptr, nullptr, nullptr, nullptr, buf0, N);
  r27_alar_kernel<<<nb4, 256, 0, stream>>>(buf0, attl2, attr2, al, ar, N);
  r27_agg_kernel<<<nb4, 256, 0, stream>>>(buf0, al, ar, rowptr, csr, b2, g2, be2, m2, v2, buf1, N);

  // fc1 + BN3 + ReLU ; fc2 + BN4 + ReLU ; fc3 (fp32 out)
  r27_gemm_kernel<HDIM, true><<<gb, 128, 0, stream>>>(buf1, fcw1, fcb1, g3, be3, m3, v3, buf0, N);
  r27_gemm_kernel<HDIM, true><<<gb, 128, 0, stream>>>(buf0, fcw2, fcb2, g4, be4, m4, v4, buf1, N);
  r27_fc3_kernel<<<nb4, 256, 0, stream>>>(buf1, fcw3, fcb3, (float*)d_out, N);
}